// Round 3
// baseline (429.014 us; speedup 1.0000x reference)
//
#include <hip/hip_runtime.h>
#include <hip/hip_bf16.h>

// Switch-Transformer FFN, top-1 routing. B=4,S=4096,D=1024,F=2048,E=8.
// Pipeline: router_logits | bucketize | W1/W2 transpose->bf16 |
// grouped GEMM1/GEMM2 in 256x256 deep-pipeline MFMA template:
//   BK=32, 4-deep LDS ring (128KB), counted vmcnt(6), raw barriers,
//   setprio around MFMA clusters, XOR-swizzled LDS (2-way = free).

typedef __attribute__((ext_vector_type(8))) short short8;
typedef __attribute__((ext_vector_type(4))) float f32x4;

struct __align__(8) us4 { unsigned short x, y, z, w; };

__device__ __forceinline__ void gload16(const void* g, void* l) {
  __builtin_amdgcn_global_load_lds(
      (const __attribute__((address_space(1))) unsigned int*)g,
      (__attribute__((address_space(3))) unsigned int*)l, 16, 0, 0);
}

__device__ __forceinline__ unsigned short f2b(float f) {
  union { float f; unsigned u; } v; v.f = f;
  unsigned r = v.u + 0x7FFFu + ((v.u >> 16) & 1u);   // RNE
  return (unsigned short)(r >> 16);
}

// ---------------- router: logits, softmax top-1 weight + expert id, x->bf16 -
__global__ __launch_bounds__(256) void router_logits(
    const float* __restrict__ x, const float* __restrict__ Wr,
    const float* __restrict__ br, float* __restrict__ wts,
    int* __restrict__ eidx, unsigned short* __restrict__ xb)
{
  const int lane = threadIdx.x & 63;
  const int wid  = threadIdx.x >> 6;
  const int t = blockIdx.x * 4 + wid;          // one wave per token

  const float4* x4 = (const float4*)(x + (size_t)t * 1024);
  float acc[8];
#pragma unroll
  for (int e = 0; e < 8; ++e) acc[e] = 0.f;
  float4 xv[4];
#pragma unroll
  for (int i = 0; i < 4; ++i) {
    float4 v = x4[lane + 64 * i];
    xv[i] = v;
    const int d = (lane + 64 * i) * 4;
    const float* wr = Wr + (size_t)d * 8;
    float xs[4] = {v.x, v.y, v.z, v.w};
#pragma unroll
    for (int j = 0; j < 4; ++j) {
      float4 w0 = *(const float4*)(wr + j * 8);
      float4 w1 = *(const float4*)(wr + j * 8 + 4);
      acc[0] += xs[j] * w0.x; acc[1] += xs[j] * w0.y;
      acc[2] += xs[j] * w0.z; acc[3] += xs[j] * w0.w;
      acc[4] += xs[j] * w1.x; acc[5] += xs[j] * w1.y;
      acc[6] += xs[j] * w1.z; acc[7] += xs[j] * w1.w;
    }
  }
#pragma unroll
  for (int i = 0; i < 4; ++i) {
    us4 o;
    o.x = f2b(xv[i].x); o.y = f2b(xv[i].y); o.z = f2b(xv[i].z); o.w = f2b(xv[i].w);
    *(us4*)(xb + (size_t)t * 1024 + (size_t)(lane + 64 * i) * 4) = o;
  }
#pragma unroll
  for (int e = 0; e < 8; ++e) {
    float v = acc[e];
#pragma unroll
    for (int m = 32; m; m >>= 1) v += __shfl_xor(v, m, 64);
    acc[e] = v;
  }
  if (lane == 0) {
    float lg[8];
#pragma unroll
    for (int e = 0; e < 8; ++e) lg[e] = acc[e] + br[e];
    float mx = lg[0]; int bi = 0;
#pragma unroll
    for (int e = 1; e < 8; ++e) if (lg[e] > mx) { mx = lg[e]; bi = e; }
    float s = 0.f;
#pragma unroll
    for (int e = 0; e < 8; ++e) s += expf(lg[e] - mx);
    wts[t]  = 1.0f / s;
    eidx[t] = bi;
  }
}

// ---------------- bucketize: LDS histogram + 8 global atomics per block -----
__global__ __launch_bounds__(256) void bucketize(
    const int* __restrict__ eidx, int* __restrict__ cnt, int* __restrict__ list)
{
  __shared__ int lcnt[8], base[8];
  const int tid = threadIdx.x;
  if (tid < 8) lcnt[tid] = 0;
  __syncthreads();
  const int t = blockIdx.x * 256 + tid;
  const int e = eidx[t];
  const int lpos = atomicAdd(&lcnt[e], 1);
  __syncthreads();
  if (tid < 8) base[tid] = atomicAdd(&cnt[tid], lcnt[tid]);
  __syncthreads();
  list[e * 16384 + base[e] + lpos] = t;
}

// ---------------- W[k][n] fp32 -> Wt[n][k] bf16 (per expert) ----------------
__global__ __launch_bounds__(256) void transpose_cvt(
    const float* __restrict__ W, unsigned short* __restrict__ Wt, int K, int N)
{
  __shared__ float tl[64][65];
  const int e = blockIdx.z;
  const float* Wp = W + (size_t)e * K * N;
  unsigned short* Wtp = Wt + (size_t)e * K * N;
  const int k0 = blockIdx.y * 64, n0 = blockIdx.x * 64;
  const int r = threadIdx.x >> 4, c4 = (threadIdx.x & 15) * 4;
#pragma unroll
  for (int i = 0; i < 4; ++i) {
    float4 v = *(const float4*)(Wp + (size_t)(k0 + r + i * 16) * N + n0 + c4);
    tl[r + i * 16][c4 + 0] = v.x; tl[r + i * 16][c4 + 1] = v.y;
    tl[r + i * 16][c4 + 2] = v.z; tl[r + i * 16][c4 + 3] = v.w;
  }
  __syncthreads();
#pragma unroll
  for (int i = 0; i < 4; ++i) {
    const int n = r + i * 16;
    us4 o;
    o.x = f2b(tl[c4 + 0][n]); o.y = f2b(tl[c4 + 1][n]);
    o.z = f2b(tl[c4 + 2][n]); o.w = f2b(tl[c4 + 3][n]);
    *(us4*)(Wtp + (size_t)(n0 + n) * K + k0 + c4) = o;
  }
}

// ---------------- grouped GEMM, 256x256 tile, BK=32, 4-deep pipeline --------
// LDS (dynamic, 133120 B):
//   [0..65535]      A ring: 4 bufs x [256 rows][32 k] bf16 (16 KB each)
//   [65536..131071] B ring: same
//   [131072..]      tok[256] int, wt[256] float
// Swizzle: 16B-slot s of row r holds global chunk s ^ ((r>>1)&3).
// Schedule per K-tile T (2 phases): stage A(T+3) in ph0, B(T+3) in ph1;
// vmcnt(6) once per tile. Certification distance >= 4 phases.
template <int K, int N, int EPI>
__global__ __launch_bounds__(512, 2) void gemm_moe8(
    const unsigned short* __restrict__ A,    // [*, K] bf16, rows gathered
    const unsigned short* __restrict__ Bt,   // [8][N][K] bf16
    const float* __restrict__ bias,          // [8][N]
    const int* __restrict__ cnt, const int* __restrict__ list,
    const float* __restrict__ wts, void* __restrict__ outp)
{
  constexpr int NT = K / 32;
  extern __shared__ float4 dynls[];
  char* lds = (char*)dynls;
  char* ldsA = lds;
  char* ldsB = lds + 65536;
  int*   tok = (int*)(lds + 131072);
  float* wt  = (float*)(lds + 132096);

  const int tid  = threadIdx.x;
  const int lane = tid & 63, wid = tid >> 6;
  const int wr = wid >> 2, wc = wid & 3;     // wave tile: rows wr*128, cols wc*64
  const int e = blockIdx.z;
  const int cnt_e = cnt[e];
  const int row0 = blockIdx.y * 256;
  if (row0 >= cnt_e) return;
  const int n0 = blockIdx.x * 256;

  if (tid < 256) {
    const int s = row0 + tid;
    const int idx = (s < cnt_e) ? s : (cnt_e - 1);
    const int t = list[e * 16384 + idx];
    tok[tid] = t;
    wt[tid]  = (EPI == 2) ? wts[t] : 0.f;
  }
  __syncthreads();

  // --- staging pointers: thread covers rows {srow, 128+srow}, slot schunk
  const int srow = tid >> 2, schunk = tid & 3;
  const int ce = (schunk ^ ((srow >> 1) & 3)) * 8;   // pre-swizzled global chunk
  const unsigned short* aP0 = A + (size_t)tok[srow] * K + ce;
  const unsigned short* aP1 = A + (size_t)tok[128 + srow] * K + ce;
  const unsigned short* bP0 = Bt + ((size_t)e * N + n0 + srow) * K + ce;
  const unsigned short* bP1 = Bt + ((size_t)e * N + n0 + 128 + srow) * K + ce;

  // --- fragment read base (swizzled): row = .. + (lane&15), slot = lane>>4
  const int l15 = lane & 15;
  const int laneoff = l15 * 64 + (((lane >> 4) ^ ((l15 >> 1) & 3)) << 4);
  const char* aFragB = ldsA + wr * 8192 + laneoff;   // + buf*16384 + m*1024
  const char* bFragB = ldsB + wc * 4096 + laneoff;   // + buf*16384 + nf*1024

  f32x4 acc[8][4];
#pragma unroll
  for (int m = 0; m < 8; ++m)
#pragma unroll
    for (int n = 0; n < 4; ++n) acc[m][n] = (f32x4){0.f, 0.f, 0.f, 0.f};

#define STAGE_A(SB, T) do { \
    char* d_ = ldsA + (SB) * 16384 + (wid << 10); \
    gload16(aP0 + (size_t)(T) * 32, d_); \
    gload16(aP1 + (size_t)(T) * 32, d_ + 8192); } while (0)
#define STAGE_B(SB, T) do { \
    char* d_ = ldsB + (SB) * 16384 + (wid << 10); \
    gload16(bP0 + (size_t)(T) * 32, d_); \
    gload16(bP1 + (size_t)(T) * 32, d_ + 8192); } while (0)

  // --- prologue: tiles 0,1,2 (order A0 B0 A1 B1 A2 B2 = 12 loads)
  STAGE_A(0, 0); STAGE_B(0, 0);
  STAGE_A(1, 1); STAGE_B(1, 1);
  STAGE_A(2, 2); STAGE_B(2, 2);
  asm volatile("s_waitcnt vmcnt(8)" ::: "memory");   // tile 0 landed
  __builtin_amdgcn_s_barrier();

  short8 aF[8], bF[4];
#pragma unroll 1
  for (int T = 0; T < NT; ++T) {
    const int buf = T & 3;
    const int st  = (T + 3 < NT) ? T + 3 : NT - 1;   // clamped dummy at tail
    const int sb  = (T + 3) & 3;
    const char* bA = aFragB + buf * 16384;
    const char* bB = bFragB + buf * 16384;
    // ---- phase 0: read A frags (held for both phases) + B nf=0,1
#pragma unroll
    for (int m = 0; m < 8; ++m) aF[m] = *(const short8*)(bA + m * 1024);
    bF[0] = *(const short8*)(bB);
    bF[1] = *(const short8*)(bB + 1024);
    STAGE_A(sb, st);
    asm volatile("s_waitcnt vmcnt(6)" ::: "memory"); // forces tile T+1 landed
    __builtin_amdgcn_s_barrier();
    __builtin_amdgcn_s_setprio(1);
#pragma unroll
    for (int m = 0; m < 8; ++m) {
      acc[m][0] = __builtin_amdgcn_mfma_f32_16x16x32_bf16(aF[m], bF[0], acc[m][0], 0, 0, 0);
      acc[m][1] = __builtin_amdgcn_mfma_f32_16x16x32_bf16(aF[m], bF[1], acc[m][1], 0, 0, 0);
    }
    __builtin_amdgcn_s_setprio(0);
    __builtin_amdgcn_s_barrier();
    // ---- phase 1: B nf=2,3
    bF[2] = *(const short8*)(bB + 2048);
    bF[3] = *(const short8*)(bB + 3072);
    STAGE_B(sb, st);
    __builtin_amdgcn_s_barrier();
    __builtin_amdgcn_s_setprio(1);
#pragma unroll
    for (int m = 0; m < 8; ++m) {
      acc[m][2] = __builtin_amdgcn_mfma_f32_16x16x32_bf16(aF[m], bF[2], acc[m][2], 0, 0, 0);
      acc[m][3] = __builtin_amdgcn_mfma_f32_16x16x32_bf16(aF[m], bF[3], acc[m][3], 0, 0, 0);
    }
    __builtin_amdgcn_s_setprio(0);
    __builtin_amdgcn_s_barrier();
  }
#undef STAGE_A
#undef STAGE_B

  // --- epilogue; C frag mapping: col = lane&15, row = (lane>>4)*4 + r
  const int cRow0 = wr * 128 + ((lane >> 4) << 2);
  const int cColB = n0 + wc * 64 + l15;
  if (EPI == 1) {
    unsigned short* H = (unsigned short*)outp;
#pragma unroll
    for (int nf = 0; nf < 4; ++nf) {
      const int col = cColB + nf * 16;
      const float bv = bias[e * N + col];
#pragma unroll
      for (int m = 0; m < 8; ++m)
#pragma unroll
        for (int r = 0; r < 4; ++r) {
          const int sl = cRow0 + m * 16 + r;
          if (row0 + sl < cnt_e) {
            float v = acc[m][nf][r] + bv;
            // tanh-form GELU (<=3e-3 abs dev from erf form; threshold 3.4e-2)
            float u = 1.5957691216f * v * (1.0f + 0.044715f * v * v); // 2*sqrt(2/pi)
            float ex = __expf(u);
            float th = 1.0f - 2.0f / (ex + 1.0f);                     // tanh(u/2*…)
            v = 0.5f * v * (1.0f + th);
            H[(size_t)tok[sl] * N + col] = f2b(v);
          }
        }
    }
  } else {
    float* O = (float*)outp;
#pragma unroll
    for (int nf = 0; nf < 4; ++nf) {
      const int col = cColB + nf * 16;
      const float bv = bias[e * N + col];
#pragma unroll
      for (int m = 0; m < 8; ++m)
#pragma unroll
        for (int r = 0; r < 4; ++r) {
          const int sl = cRow0 + m * 16 + r;
          if (row0 + sl < cnt_e) {
            O[(size_t)tok[sl] * N + col] = (acc[m][nf][r] + bv) * wt[sl];
          }
        }
    }
  }
}

// ---------------------------------------------------------------------------
extern "C" void kernel_launch(void* const* d_in, const int* in_sizes, int n_in,
                              void* d_out, int out_size, void* d_ws, size_t ws_size,
                              hipStream_t stream) {
  const float* x  = (const float*)d_in[0];   // [4,4096,1024]
  const float* Wr = (const float*)d_in[1];   // [1024,8]
  const float* br = (const float*)d_in[2];   // [8]
  const float* W1 = (const float*)d_in[3];   // [8,1024,2048]
  const float* b1 = (const float*)d_in[4];   // [8,2048]
  const float* W2 = (const float*)d_in[5];   // [8,2048,1024]
  const float* b2 = (const float*)d_in[6];   // [8,1024]

  char* ws = (char*)d_ws;
  int*   cnt  = (int*)ws;                                  // 8 ints
  float* wts  = (float*)(ws + 256);                        // 16384 f32
  int*   eidx = (int*)(ws + 256 + 64 * 1024);              // 16384 int
  int*   list = (int*)(ws + 256 + 128 * 1024);             // 8*16384 int
  unsigned short* xb  = (unsigned short*)(ws + 1024 * 1024);     // 32 MB
  unsigned short* w1t = xb  + (size_t)16384 * 1024;              // 32 MB
  unsigned short* w2t = w1t + (size_t)8 * 2048 * 1024;           // 32 MB
  unsigned short* h   = w2t + (size_t)8 * 1024 * 2048;           // 64 MB

  constexpr int LDS_BYTES = 133120;
  hipFuncSetAttribute((const void*)gemm_moe8<1024, 2048, 1>,
                      hipFuncAttributeMaxDynamicSharedMemorySize, LDS_BYTES);
  hipFuncSetAttribute((const void*)gemm_moe8<2048, 1024, 2>,
                      hipFuncAttributeMaxDynamicSharedMemorySize, LDS_BYTES);

  hipMemsetAsync(cnt, 0, 32, stream);
  router_logits<<<dim3(4096), 256, 0, stream>>>(x, Wr, br, wts, eidx, xb);
  bucketize<<<dim3(64), 256, 0, stream>>>(eidx, cnt, list);
  transpose_cvt<<<dim3(32, 16, 8), 256, 0, stream>>>(W1, w1t, 1024, 2048);
  transpose_cvt<<<dim3(16, 32, 8), 256, 0, stream>>>(W2, w2t, 2048, 1024);
  gemm_moe8<1024, 2048, 1><<<dim3(8, 64, 8), 512, LDS_BYTES, stream>>>(
      xb, w1t, b1, cnt, list, wts, (void*)h);
  gemm_moe8<2048, 1024, 2><<<dim3(4, 64, 8), 512, LDS_BYTES, stream>>>(
      h, w2t, b2, cnt, list, wts, d_out);
}

// Round 4
// 390.809 us; speedup vs baseline: 1.0978x; 1.0978x over previous
//
#include <hip/hip_runtime.h>
#include <hip/hip_bf16.h>

// Switch-Transformer FFN, top-1 routing. B=4,S=4096,D=1024,F=2048,E=8.
// Pipeline: router_logits | bucketize | gather(compact tokens->xc bf16) |
// W1/W2 transpose->bf16 | dense grouped GEMM1 (GELU, h bf16 by slot) |
// dense grouped GEMM2 (scale epi, scatter fp32 out).
// GEMMs: m97 structure (128x128, BK=32, 4 waves, dbuf LDS, 4 blocks/CU),
// verified conflict-free XOR swizzle, supertile L2 block mapping (xcd=bid&7).

typedef __attribute__((ext_vector_type(8))) short short8;
typedef __attribute__((ext_vector_type(4))) float f32x4;

struct __align__(8) us4 { unsigned short x, y, z, w; };

__device__ __forceinline__ void gload16(const void* g, void* l) {
  __builtin_amdgcn_global_load_lds(
      (const __attribute__((address_space(1))) unsigned int*)g,
      (__attribute__((address_space(3))) unsigned int*)l, 16, 0, 0);
}

__device__ __forceinline__ unsigned short f2b(float f) {
  union { float f; unsigned u; } v; v.f = f;
  unsigned r = v.u + 0x7FFFu + ((v.u >> 16) & 1u);   // RNE
  return (unsigned short)(r >> 16);
}

// ---------------- router: logits, softmax top-1 weight + expert id ----------
__global__ __launch_bounds__(256) void router_logits(
    const float* __restrict__ x, const float* __restrict__ Wr,
    const float* __restrict__ br, float* __restrict__ wts,
    int* __restrict__ eidx)
{
  const int lane = threadIdx.x & 63;
  const int wid  = threadIdx.x >> 6;
  const int t = blockIdx.x * 4 + wid;          // one wave per token

  const float4* x4 = (const float4*)(x + (size_t)t * 1024);
  float acc[8];
#pragma unroll
  for (int e = 0; e < 8; ++e) acc[e] = 0.f;
#pragma unroll
  for (int i = 0; i < 4; ++i) {
    float4 v = x4[lane + 64 * i];
    const int d = (lane + 64 * i) * 4;
    const float* wr = Wr + (size_t)d * 8;
    float xs[4] = {v.x, v.y, v.z, v.w};
#pragma unroll
    for (int j = 0; j < 4; ++j) {
      float4 w0 = *(const float4*)(wr + j * 8);
      float4 w1 = *(const float4*)(wr + j * 8 + 4);
      acc[0] += xs[j] * w0.x; acc[1] += xs[j] * w0.y;
      acc[2] += xs[j] * w0.z; acc[3] += xs[j] * w0.w;
      acc[4] += xs[j] * w1.x; acc[5] += xs[j] * w1.y;
      acc[6] += xs[j] * w1.z; acc[7] += xs[j] * w1.w;
    }
  }
#pragma unroll
  for (int e = 0; e < 8; ++e) {
    float v = acc[e];
#pragma unroll
    for (int m = 32; m; m >>= 1) v += __shfl_xor(v, m, 64);
    acc[e] = v;
  }
  if (lane == 0) {
    float lg[8];
#pragma unroll
    for (int e = 0; e < 8; ++e) lg[e] = acc[e] + br[e];
    float mx = lg[0]; int bi = 0;
#pragma unroll
    for (int e = 1; e < 8; ++e) if (lg[e] > mx) { mx = lg[e]; bi = e; }  // first-max == argmax
    float s = 0.f;
#pragma unroll
    for (int e = 0; e < 8; ++e) s += expf(lg[e] - mx);
    wts[t]  = 1.0f / s;
    eidx[t] = bi;
  }
}

// ---------------- bucketize: LDS histogram + 8 global atomics per block -----
__global__ __launch_bounds__(256) void bucketize(
    const int* __restrict__ eidx, int* __restrict__ cnt, int* __restrict__ list)
{
  __shared__ int lcnt[8], base[8];
  const int tid = threadIdx.x;
  if (tid < 8) lcnt[tid] = 0;
  __syncthreads();
  const int t = blockIdx.x * 256 + tid;
  const int e = eidx[t];
  const int lpos = atomicAdd(&lcnt[e], 1);
  __syncthreads();
  if (tid < 8) base[tid] = atomicAdd(&cnt[tid], lcnt[tid]);
  __syncthreads();
  list[e * 16384 + base[e] + lpos] = t;
}

// ---------------- gather: xc[slot] = bf16(x[tok]), dense per-expert rows ----
__global__ __launch_bounds__(256) void gather_compact(
    const float* __restrict__ x, const int* __restrict__ cnt,
    const int* __restrict__ list, unsigned short* __restrict__ xc)
{
  const int lane = threadIdx.x & 63, wid = threadIdx.x >> 6;
  const int g = blockIdx.x * 4 + wid;          // global slot, < 16384 always
  int fe = -1, fpre = 0, pr = 0;
#pragma unroll
  for (int i = 0; i < 8; ++i) {
    const int c = cnt[i];
    if (fe < 0 && g < pr + c) { fe = i; fpre = pr; }
    pr += c;
  }
  const int tok = list[fe * 16384 + (g - fpre)];
  const float4* xs = (const float4*)(x + (size_t)tok * 1024);
  unsigned short* xd = xc + (size_t)g * 1024;
#pragma unroll
  for (int i = 0; i < 4; ++i) {
    float4 v = xs[lane + 64 * i];
    us4 o;
    o.x = f2b(v.x); o.y = f2b(v.y); o.z = f2b(v.z); o.w = f2b(v.w);
    *(us4*)(xd + (size_t)(lane + 64 * i) * 4) = o;
  }
}

// ---------------- W[k][n] fp32 -> Wt[n][k] bf16 (per expert) ----------------
__global__ __launch_bounds__(256) void transpose_cvt(
    const float* __restrict__ W, unsigned short* __restrict__ Wt, int K, int N)
{
  __shared__ float tl[64][65];
  const int e = blockIdx.z;
  const float* Wp = W + (size_t)e * K * N;
  unsigned short* Wtp = Wt + (size_t)e * K * N;
  const int k0 = blockIdx.y * 64, n0 = blockIdx.x * 64;
  const int r = threadIdx.x >> 4, c4 = (threadIdx.x & 15) * 4;
#pragma unroll
  for (int i = 0; i < 4; ++i) {
    float4 v = *(const float4*)(Wp + (size_t)(k0 + r + i * 16) * N + n0 + c4);
    tl[r + i * 16][c4 + 0] = v.x; tl[r + i * 16][c4 + 1] = v.y;
    tl[r + i * 16][c4 + 2] = v.z; tl[r + i * 16][c4 + 3] = v.w;
  }
  __syncthreads();
#pragma unroll
  for (int i = 0; i < 4; ++i) {
    const int n = r + i * 16;
    us4 o;
    o.x = f2b(tl[c4 + 0][n]); o.y = f2b(tl[c4 + 1][n]);
    o.z = f2b(tl[c4 + 2][n]); o.w = f2b(tl[c4 + 3][n]);
    *(us4*)(Wtp + (size_t)(n0 + n) * K + k0 + c4) = o;
  }
}

// ---------------- dense grouped GEMM, 128x128 tile, m97 structure -----------
// A rows are DENSE (slot-compacted). Supertile decode: bid -> xcd-chunked
// position p -> (expert, supertile, local m,n). Supertile = 2^LM x 2^LN
// blocks; A+B working set fits one XCD L2 (4 MB).
// Swizzle (verified 0-conflict): 16B-slot s of row r holds chunk s^((r>>1)&3).
// EPI==1: h[pre+row][col] = bf16(gelu(acc+b1));  EPI==2: scatter fp32 * wt.
template <int K, int N, int EPI, int LM_BITS, int LN_BITS>
__global__ __launch_bounds__(256) void gemm_moe(
    const unsigned short* __restrict__ A,    // [16384][K] bf16 dense slots
    const unsigned short* __restrict__ Bt,   // [8][N][K] bf16
    const float* __restrict__ bias,          // [8][N]
    const int* __restrict__ cnt, const int* __restrict__ list,
    const float* __restrict__ wts, void* __restrict__ outp, int cpx)
{
  constexpr int BK = 32, NKT = K / BK;
  constexpr int N_ST = (N / 128) >> LN_BITS;           // = 2 for both GEMMs
  constexpr int ST_BITS = LM_BITS + LN_BITS;
  __shared__ __align__(16) unsigned short sm[2][2][128][BK];
  __shared__ int tok_s[128];
  __shared__ float wt_s[128];

  // ---- supertile decode (wave-uniform scalar) ----
  const int bid = blockIdx.x;
  const int p = (bid & 7) * cpx + (bid >> 3);
  const int st = p >> ST_BITS, q = p & ((1 << ST_BITS) - 1);
  int e, pre, mB, cnte;
  {
    int sb = 0, pr = 0, fe = -1, fsb = 0, fpre = 0, fmB = 0, fc = 0;
#pragma unroll
    for (int i = 0; i < 8; ++i) {
      const int c = cnt[i];
      const int mb_i = (c + 127) >> 7;
      const int st_i = ((mb_i + (1 << LM_BITS) - 1) >> LM_BITS) * N_ST;
      if (fe < 0 && st < sb + st_i) { fe = i; fsb = sb; fpre = pr; fmB = mb_i; fc = c; }
      sb += st_i; pr += c;
    }
    if (fe < 0) return;
    e = fe; pre = fpre; mB = fmB; cnte = fc;
    const int stl = st - fsb;
    const int mb = ((stl >> 1) << LM_BITS) + (q & ((1 << LM_BITS) - 1));
    if (mb >= mB) return;
    const int nb = ((stl & 1) << LN_BITS) + (q >> LM_BITS);
    pre += 0;
    tok_s[0] = tok_s[0];  // no-op; keeps arrays alive for EPI1 too
    // stash in registers:
    mB = mb; cnte = fc;   // reuse: mB now holds mb
    e = fe;
    // row0/n0 below
    wt_s[0] = wt_s[0];
    // fallthrough with mb in mB, nb via recompute:
    const int row0_ = mb << 7, n0_ = nb << 7;
    // use locals:
    #define ROW0 row0_
    #define N0 n0_

  const int tid  = threadIdx.x;
  const int lane = tid & 63, wid = tid >> 6;
  const int l15  = lane & 15;

  if (EPI == 2) {
    if (tid < 128) {
      const int s = ROW0 + tid;
      if (s < cnte) {
        const int t = list[e * 16384 + s];
        tok_s[tid] = t;
        wt_s[tid]  = wts[t];
      } else { tok_s[tid] = 0; wt_s[tid] = 0.f; }
    }
  }

  // ---- staging: wave covers rows wid*16+(lane>>2) and +64; chunk lane&3 ----
  const int ce = (((lane & 3) ^ ((lane >> 3) & 3))) * 8;   // pre-swizzled chunk
  const int sr = wid * 16 + (lane >> 2);
  const int ar0 = min(pre + ROW0 + sr, 16383);
  const int ar1 = min(pre + ROW0 + 64 + sr, 16383);
  const unsigned short* aP0 = A + (size_t)ar0 * K + ce;
  const unsigned short* aP1 = A + (size_t)ar1 * K + ce;
  const unsigned short* bP0 = Bt + ((size_t)e * N + N0 + sr) * K + ce;
  const unsigned short* bP1 = Bt + ((size_t)e * N + N0 + 64 + sr) * K + ce;

  // ---- fragment read offsets ----
  const int foff = (((lane >> 4) ^ ((l15 >> 1) & 3)) << 4);  // bytes
  const int mrow = (wid >> 1) * 64 + l15;
  const int nrow = (wid & 1) * 64 + l15;

  f32x4 acc[4][4];
#pragma unroll
  for (int i = 0; i < 4; ++i)
#pragma unroll
    for (int j = 0; j < 4; ++j) acc[i][j] = (f32x4){0.f, 0.f, 0.f, 0.f};

  auto stage = [&](int buf, int kt) {
    const size_t ko = (size_t)kt * BK;
    gload16(aP0 + ko, &sm[buf][0][wid * 16][0]);
    gload16(aP1 + ko, &sm[buf][0][64 + wid * 16][0]);
    gload16(bP0 + ko, &sm[buf][1][wid * 16][0]);
    gload16(bP1 + ko, &sm[buf][1][64 + wid * 16][0]);
  };
  auto compute = [&](int buf) {
    short8 af[4], bfr[4];
#pragma unroll
    for (int mf = 0; mf < 4; ++mf)
      af[mf] = *(const short8*)((const char*)&sm[buf][0][mrow + mf * 16][0] + foff);
#pragma unroll
    for (int nf = 0; nf < 4; ++nf)
      bfr[nf] = *(const short8*)((const char*)&sm[buf][1][nrow + nf * 16][0] + foff);
#pragma unroll
    for (int mf = 0; mf < 4; ++mf)
#pragma unroll
      for (int nf = 0; nf < 4; ++nf)
        acc[mf][nf] = __builtin_amdgcn_mfma_f32_16x16x32_bf16(
            af[mf], bfr[nf], acc[mf][nf], 0, 0, 0);
  };

  stage(0, 0);
  __syncthreads();
#pragma unroll 1
  for (int kt = 0; kt < NKT; kt += 2) {
    stage(1, kt + 1);
    compute(0);
    __syncthreads();
    if (kt + 2 < NKT) stage(0, kt + 2);
    compute(1);
    __syncthreads();
  }

  // ---- epilogue; C mapping: col = lane&15, row = (lane>>4)*4 + r ----
  const int cRow0 = (wid >> 1) * 64 + ((lane >> 4) << 2);
  const int cColB = N0 + (wid & 1) * 64 + l15;
  float bv[4];
#pragma unroll
  for (int nf = 0; nf < 4; ++nf) bv[nf] = bias[e * N + cColB + nf * 16];

  if (EPI == 1) {
    unsigned short* H = (unsigned short*)outp;
#pragma unroll
    for (int m = 0; m < 4; ++m)
#pragma unroll
      for (int r = 0; r < 4; ++r) {
        const int sl = cRow0 + m * 16 + r;
        if (ROW0 + sl < cnte) {
          const size_t rp = (size_t)(pre + ROW0 + sl) * N + cColB;
#pragma unroll
          for (int nf = 0; nf < 4; ++nf) {           // nf innermost: 128B span
            float v = acc[m][nf][r] + bv[nf];
            v = 0.5f * v * (1.0f + erff(v * 0.70710678118654752f));
            H[rp + nf * 16] = f2b(v);
          }
        }
      }
  } else {
    float* O = (float*)outp;
#pragma unroll
    for (int m = 0; m < 4; ++m)
#pragma unroll
      for (int r = 0; r < 4; ++r) {
        const int sl = cRow0 + m * 16 + r;
        if (ROW0 + sl < cnte) {
          const size_t rp = (size_t)tok_s[sl] * N + cColB;
          const float w = wt_s[sl];
#pragma unroll
          for (int nf = 0; nf < 4; ++nf)
            O[rp + nf * 16] = (acc[m][nf][r] + bv[nf]) * w;
        }
      }
  }
  #undef ROW0
  #undef N0
  }
}

// ---------------------------------------------------------------------------
extern "C" void kernel_launch(void* const* d_in, const int* in_sizes, int n_in,
                              void* d_out, int out_size, void* d_ws, size_t ws_size,
                              hipStream_t stream) {
  const float* x  = (const float*)d_in[0];   // [4,4096,1024]
  const float* Wr = (const float*)d_in[1];   // [1024,8]
  const float* br = (const float*)d_in[2];   // [8]
  const float* W1 = (const float*)d_in[3];   // [8,1024,2048]
  const float* b1 = (const float*)d_in[4];   // [8,2048]
  const float* W2 = (const float*)d_in[5];   // [8,2048,1024]
  const float* b2 = (const float*)d_in[6];   // [8,1024]

  char* ws = (char*)d_ws;
  int*   cnt  = (int*)ws;                                  // 8 ints
  float* wts  = (float*)(ws + 256);                        // 16384 f32
  int*   eidx = (int*)(ws + 256 + 64 * 1024);              // 16384 int
  int*   list = (int*)(ws + 256 + 128 * 1024);             // 8*16384 int
  unsigned short* xc  = (unsigned short*)(ws + 1024 * 1024);     // 32 MB dense
  unsigned short* w1t = xc  + (size_t)16384 * 1024;              // 32 MB
  unsigned short* w2t = w1t + (size_t)8 * 2048 * 1024;           // 32 MB
  unsigned short* h   = w2t + (size_t)8 * 1024 * 2048;           // 64 MB

  hipMemsetAsync(cnt, 0, 32, stream);
  router_logits<<<dim3(4096), 256, 0, stream>>>(x, Wr, br, wts, eidx);
  bucketize<<<dim3(64), 256, 0, stream>>>(eidx, cnt, list);
  gather_compact<<<dim3(4096), 256, 0, stream>>>(x, cnt, list, xc);
  transpose_cvt<<<dim3(32, 16, 8), 256, 0, stream>>>(W1, w1t, 1024, 2048);
  transpose_cvt<<<dim3(16, 32, 8), 256, 0, stream>>>(W2, w2t, 2048, 1024);
  // gemm1: supertile 8x8 blocks (1024x1024 out, A+B = 4MB = L2). worst 46 st.
  gemm_moe<1024, 2048, 1, 3, 3><<<dim3(2944), 256, 0, stream>>>(
      xc, w1t, b1, cnt, list, wts, (void*)h, 2944 / 8);
  // gemm2: supertile 4x4 blocks (512x512 out, A+B = 4MB = L2). worst 78 st.
  gemm_moe<2048, 1024, 2, 2, 2><<<dim3(1248), 256, 0, stream>>>(
      h, w2t, b2, cnt, list, wts, d_out, 1248 / 8);
}

// Round 5
// 369.979 us; speedup vs baseline: 1.1596x; 1.0563x over previous
//
#include <hip/hip_runtime.h>
#include <hip/hip_bf16.h>

// Switch-Transformer FFN, top-1 routing. B=4,S=4096,D=1024,F=2048,E=8.
// Pipeline: router_logits | bucketize | gather(compact->xc bf16) |
// W1/W2 transpose->bf16 | grouped GEMM1 (GELU, h bf16 by slot) |
// grouped GEMM2 (scale epi, scatter fp32).
// GEMM: 256x256 tile, BK=32, 8 waves, ring-4 LDS (128KB), counted vmcnt(8)
// (never 0 in-loop), raw barriers + setprio, 0-conflict XOR swizzle,
// dense A (compacted), supertile-free L2 mapping via XCD-chunked nb-fast.

typedef __attribute__((ext_vector_type(8))) short short8;
typedef __attribute__((ext_vector_type(4))) float f32x4;

struct __align__(8) us4 { unsigned short x, y, z, w; };

__device__ __forceinline__ void gload16(const void* g, void* l) {
  __builtin_amdgcn_global_load_lds(
      (const __attribute__((address_space(1))) unsigned int*)g,
      (__attribute__((address_space(3))) unsigned int*)l, 16, 0, 0);
}

__device__ __forceinline__ unsigned short f2b(float f) {
  union { float f; unsigned u; } v; v.f = f;
  unsigned r = v.u + 0x7FFFu + ((v.u >> 16) & 1u);   // RNE
  return (unsigned short)(r >> 16);
}

// ---------------- router: logits, softmax top-1 weight + expert id ----------
__global__ __launch_bounds__(256) void router_logits(
    const float* __restrict__ x, const float* __restrict__ Wr,
    const float* __restrict__ br, float* __restrict__ wts,
    int* __restrict__ eidx)
{
  const int lane = threadIdx.x & 63;
  const int wid  = threadIdx.x >> 6;
  const int t = blockIdx.x * 4 + wid;

  const float4* x4 = (const float4*)(x + (size_t)t * 1024);
  float acc[8];
#pragma unroll
  for (int e = 0; e < 8; ++e) acc[e] = 0.f;
#pragma unroll
  for (int i = 0; i < 4; ++i) {
    float4 v = x4[lane + 64 * i];
    const int d = (lane + 64 * i) * 4;
    const float* wr = Wr + (size_t)d * 8;
    float xs[4] = {v.x, v.y, v.z, v.w};
#pragma unroll
    for (int j = 0; j < 4; ++j) {
      float4 w0 = *(const float4*)(wr + j * 8);
      float4 w1 = *(const float4*)(wr + j * 8 + 4);
      acc[0] += xs[j] * w0.x; acc[1] += xs[j] * w0.y;
      acc[2] += xs[j] * w0.z; acc[3] += xs[j] * w0.w;
      acc[4] += xs[j] * w1.x; acc[5] += xs[j] * w1.y;
      acc[6] += xs[j] * w1.z; acc[7] += xs[j] * w1.w;
    }
  }
#pragma unroll
  for (int e = 0; e < 8; ++e) {
    float v = acc[e];
#pragma unroll
    for (int m = 32; m; m >>= 1) v += __shfl_xor(v, m, 64);
    acc[e] = v;
  }
  if (lane == 0) {
    float lg[8];
#pragma unroll
    for (int e = 0; e < 8; ++e) lg[e] = acc[e] + br[e];
    float mx = lg[0]; int bi = 0;
#pragma unroll
    for (int e = 1; e < 8; ++e) if (lg[e] > mx) { mx = lg[e]; bi = e; }  // first-max == argmax
    float s = 0.f;
#pragma unroll
    for (int e = 0; e < 8; ++e) s += expf(lg[e] - mx);
    wts[t]  = 1.0f / s;
    eidx[t] = bi;
  }
}

// ---------------- bucketize ----------
__global__ __launch_bounds__(256) void bucketize(
    const int* __restrict__ eidx, int* __restrict__ cnt, int* __restrict__ list)
{
  __shared__ int lcnt[8], base[8];
  const int tid = threadIdx.x;
  if (tid < 8) lcnt[tid] = 0;
  __syncthreads();
  const int t = blockIdx.x * 256 + tid;
  const int e = eidx[t];
  const int lpos = atomicAdd(&lcnt[e], 1);
  __syncthreads();
  if (tid < 8) base[tid] = atomicAdd(&cnt[tid], lcnt[tid]);
  __syncthreads();
  list[e * 16384 + base[e] + lpos] = t;
}

// ---------------- gather: xc[slot] = bf16(x[tok]) ----------
__global__ __launch_bounds__(256) void gather_compact(
    const float* __restrict__ x, const int* __restrict__ cnt,
    const int* __restrict__ list, unsigned short* __restrict__ xc)
{
  const int lane = threadIdx.x & 63, wid = threadIdx.x >> 6;
  const int g = blockIdx.x * 4 + wid;
  int fe = -1, fpre = 0, pr = 0;
#pragma unroll
  for (int i = 0; i < 8; ++i) {
    const int c = cnt[i];
    if (fe < 0 && g < pr + c) { fe = i; fpre = pr; }
    pr += c;
  }
  const int tok = list[fe * 16384 + (g - fpre)];
  const float4* xs = (const float4*)(x + (size_t)tok * 1024);
  unsigned short* xd = xc + (size_t)g * 1024;
#pragma unroll
  for (int i = 0; i < 4; ++i) {
    float4 v = xs[lane + 64 * i];
    us4 o;
    o.x = f2b(v.x); o.y = f2b(v.y); o.z = f2b(v.z); o.w = f2b(v.w);
    *(us4*)(xd + (size_t)(lane + 64 * i) * 4) = o;
  }
}

// ---------------- W[k][n] fp32 -> Wt[n][k] bf16 ----------
__global__ __launch_bounds__(256) void transpose_cvt(
    const float* __restrict__ W, unsigned short* __restrict__ Wt, int K, int N)
{
  __shared__ float tl[64][65];
  const int e = blockIdx.z;
  const float* Wp = W + (size_t)e * K * N;
  unsigned short* Wtp = Wt + (size_t)e * K * N;
  const int k0 = blockIdx.y * 64, n0 = blockIdx.x * 64;
  const int r = threadIdx.x >> 4, c4 = (threadIdx.x & 15) * 4;
#pragma unroll
  for (int i = 0; i < 4; ++i) {
    float4 v = *(const float4*)(Wp + (size_t)(k0 + r + i * 16) * N + n0 + c4);
    tl[r + i * 16][c4 + 0] = v.x; tl[r + i * 16][c4 + 1] = v.y;
    tl[r + i * 16][c4 + 2] = v.z; tl[r + i * 16][c4 + 3] = v.w;
  }
  __syncthreads();
#pragma unroll
  for (int i = 0; i < 4; ++i) {
    const int n = r + i * 16;
    us4 o;
    o.x = f2b(tl[c4 + 0][n]); o.y = f2b(tl[c4 + 1][n]);
    o.z = f2b(tl[c4 + 2][n]); o.w = f2b(tl[c4 + 3][n]);
    *(us4*)(Wtp + (size_t)(n0 + n) * K + k0 + c4) = o;
  }
}

// ---------------- grouped GEMM: 256x256, BK=32, ring-4, counted vmcnt -------
// LDS: A ring 4x[256][32]bf16 (4x16KB) @0; B ring @65536; tok@131072 wt@132096.
// Swizzle (measured 0-conflict): 16B-slot c of row r holds chunk c^((r>>1)&3).
// Schedule per tile T: ph0{ds A8+B2 | STG_A(T+3) | bar | lgkm0 | 16 MFMA | bar}
//                      ph1{ds B2    | STG_B(T+3) | vmcnt(8) | bar | lgkm0 | 16 MFMA | bar}
// vmcnt(8) certifies tile T+1 (outstanding = tiles T+2,T+3 = 8 loads). Ring
// slot (T+3)&3 == (T-1)&3 is dead by then. Tail restages tile NT-1 (dummy).
template <int K, int N, int EPI, int LOGNB>
__global__ __launch_bounds__(512, 2) void gemm_moe8(
    const unsigned short* __restrict__ A,    // [16384][K] bf16 dense slots
    const unsigned short* __restrict__ Bt,   // [8][N][K] bf16
    const float* __restrict__ bias,          // [8][N]
    const int* __restrict__ cnt, const int* __restrict__ list,
    const float* __restrict__ wts, void* __restrict__ outp)
{
  constexpr int NT = K / 32;
  constexpr int NB = 1 << LOGNB;
  extern __shared__ char lds[];
  int*   tok_s = (int*)(lds + 131072);
  float* wt_s  = (float*)(lds + 132096);

  // ---- decode: XCD-chunked p -> (expert, mb, nb); nb fast (A-panel reuse)
  const int q = gridDim.x >> 3;
  const int p = ((int)blockIdx.x & 7) * q + ((int)blockIdx.x >> 3);
  int e = -1, pre = 0, cnte = 0, loc = p;
#pragma unroll
  for (int i = 0; i < 8; ++i) {
    const int c = cnt[i];
    const int bl = ((c + 255) >> 8) << LOGNB;
    if (e < 0) {
      if (loc < bl) { e = i; cnte = c; }
      else { loc -= bl; pre += c; }
    }
  }
  if (e < 0) return;
  const int row0 = (loc >> LOGNB) << 8;
  const int n0   = (loc & (NB - 1)) << 8;

  const int tid = threadIdx.x;
  const int lane = tid & 63, wid = tid >> 6;
  const int wr = wid >> 2, wc = wid & 3;     // wave output: rows wr*128, cols wc*64
  const int l15 = lane & 15;

  if (EPI == 2) {
    if (tid < 256) {
      const int s = row0 + tid;
      if (s < cnte) { const int t = list[e * 16384 + s]; tok_s[tid] = t; wt_s[tid] = wts[t]; }
      else { tok_s[tid] = 0; wt_s[tid] = 0.f; }
    }
    __syncthreads();
  }

  // ---- staging: thread covers rows {srow, 128+srow}, 16B slot (tid&3)
  const int srow = tid >> 2;                 // 0..127
  const int gch  = ((tid & 3) ^ ((srow >> 1) & 3)) * 8;   // pre-swizzled chunk
  const int ar0 = min(pre + row0 + srow, 16383);
  const int ar1 = min(pre + row0 + 128 + srow, 16383);
  const unsigned short* aG0 = A + (size_t)ar0 * K + gch;
  const unsigned short* aG1 = A + (size_t)ar1 * K + gch;
  const unsigned short* bG0 = Bt + ((size_t)e * N + n0 + srow) * K + gch;
  const unsigned short* bG1 = Bt + ((size_t)e * N + n0 + 128 + srow) * K + gch;

  // ---- fragment read bases (XOR folds to per-lane constant)
  const int x = (((lane >> 4) ^ ((l15 >> 1) & 3)) << 4);
  const char* aB = lds + wr * 8192 + l15 * 64 + x;            // + slot*16384 + mf*1024
  const char* bB = lds + 65536 + wc * 4096 + l15 * 64 + x;    // + slot*16384 + nf*1024

  f32x4 acc[8][4];
#pragma unroll
  for (int m = 0; m < 8; ++m)
#pragma unroll
    for (int n = 0; n < 4; ++n) acc[m][n] = (f32x4){0.f, 0.f, 0.f, 0.f};

#define STG_A(S, T) do { \
    char* d_ = lds + (S) * 16384 + (wid << 10); \
    gload16(aG0 + (size_t)(T) * 32, d_); \
    gload16(aG1 + (size_t)(T) * 32, d_ + 8192); } while (0)
#define STG_B(S, T) do { \
    char* d_ = lds + 65536 + (S) * 16384 + (wid << 10); \
    gload16(bG0 + (size_t)(T) * 32, d_); \
    gload16(bG1 + (size_t)(T) * 32, d_ + 8192); } while (0)

  // ---- prologue: tiles 0,1,2 (12 loads); certify tile 0 (<=8 outstanding)
  STG_A(0, 0); STG_B(0, 0);
  STG_A(1, 1); STG_B(1, 1);
  STG_A(2, 2); STG_B(2, 2);
  asm volatile("s_waitcnt vmcnt(8)" ::: "memory");
  __builtin_amdgcn_s_barrier();

  short8 aF[8], bF[2];
#pragma unroll 1
  for (int T = 0; T < NT; ++T) {
    const int slot = T & 3;
    const int ss   = (T + 3) & 3;
    const int Ts   = (T + 3 < NT) ? T + 3 : NT - 1;   // dummy restage at tail
    const char* aT = aB + slot * 16384;
    const char* bT = bB + slot * 16384;
    // ---- phase 0: A frags (held both phases) + B nf=0,1
#pragma unroll
    for (int m = 0; m < 8; ++m) aF[m] = *(const short8*)(aT + m * 1024);
    bF[0] = *(const short8*)(bT);
    bF[1] = *(const short8*)(bT + 1024);
    STG_A(ss, Ts);
    __builtin_amdgcn_s_barrier();
    asm volatile("s_waitcnt lgkmcnt(0)" ::: "memory");
    __builtin_amdgcn_sched_barrier(0);
    __builtin_amdgcn_s_setprio(1);
#pragma unroll
    for (int m = 0; m < 8; ++m) {
      acc[m][0] = __builtin_amdgcn_mfma_f32_16x16x32_bf16(aF[m], bF[0], acc[m][0], 0, 0, 0);
      acc[m][1] = __builtin_amdgcn_mfma_f32_16x16x32_bf16(aF[m], bF[1], acc[m][1], 0, 0, 0);
    }
    __builtin_amdgcn_s_setprio(0);
    __builtin_amdgcn_s_barrier();
    // ---- phase 1: B nf=2,3
    bF[0] = *(const short8*)(bT + 2048);
    bF[1] = *(const short8*)(bT + 3072);
    STG_B(ss, Ts);
    asm volatile("s_waitcnt vmcnt(8)" ::: "memory");   // certify tile T+1
    __builtin_amdgcn_s_barrier();
    asm volatile("s_waitcnt lgkmcnt(0)" ::: "memory");
    __builtin_amdgcn_sched_barrier(0);
    __builtin_amdgcn_s_setprio(1);
#pragma unroll
    for (int m = 0; m < 8; ++m) {
      acc[m][2] = __builtin_amdgcn_mfma_f32_16x16x32_bf16(aF[m], bF[0], acc[m][2], 0, 0, 0);
      acc[m][3] = __builtin_amdgcn_mfma_f32_16x16x32_bf16(aF[m], bF[1], acc[m][3], 0, 0, 0);
    }
    __builtin_amdgcn_s_setprio(0);
    __builtin_amdgcn_s_barrier();
  }
#undef STG_A
#undef STG_B
  asm volatile("s_waitcnt vmcnt(0)" ::: "memory");     // drain dummy stages

  // ---- epilogue; C frag: col = lane&15, row = (lane>>4)*4 + r
  const int cRow0 = wr * 128 + ((lane >> 4) << 2);
  const int cColB = n0 + wc * 64 + l15;
  float bv[4];
#pragma unroll
  for (int nf = 0; nf < 4; ++nf) bv[nf] = bias[e * N + cColB + nf * 16];

  if (EPI == 1) {
    unsigned short* H = (unsigned short*)outp;
#pragma unroll
    for (int m = 0; m < 8; ++m)
#pragma unroll
      for (int r = 0; r < 4; ++r) {
        const int sl = cRow0 + m * 16 + r;
        if (row0 + sl < cnte) {
          const size_t rp = (size_t)(pre + row0 + sl) * N + cColB;
#pragma unroll
          for (int nf = 0; nf < 4; ++nf) {
            float v = acc[m][nf][r] + bv[nf];
            // tanh-form GELU via exp (dev <= ~1e-3 vs erf; threshold 3.4e-2)
            float u = 1.5957691216f * v * (1.0f + 0.044715f * v * v);
            float ex = __expf(u);
            float th = 1.0f - 2.0f / (ex + 1.0f);
            v = 0.5f * v * (1.0f + th);
            H[rp + nf * 16] = f2b(v);
          }
        }
      }
  } else {
    float* O = (float*)outp;
#pragma unroll
    for (int m = 0; m < 8; ++m)
#pragma unroll
      for (int r = 0; r < 4; ++r) {
        const int sl = cRow0 + m * 16 + r;
        if (row0 + sl < cnte) {
          const size_t rp = (size_t)tok_s[sl] * N + cColB;
          const float w = wt_s[sl];
#pragma unroll
          for (int nf = 0; nf < 4; ++nf)
            O[rp + nf * 16] = (acc[m][nf][r] + bv[nf]) * w;
        }
      }
  }
}

// ---------------------------------------------------------------------------
extern "C" void kernel_launch(void* const* d_in, const int* in_sizes, int n_in,
                              void* d_out, int out_size, void* d_ws, size_t ws_size,
                              hipStream_t stream) {
  const float* x  = (const float*)d_in[0];   // [4,4096,1024]
  const float* Wr = (const float*)d_in[1];   // [1024,8]
  const float* br = (const float*)d_in[2];   // [8]
  const float* W1 = (const float*)d_in[3];   // [8,1024,2048]
  const float* b1 = (const float*)d_in[4];   // [8,2048]
  const float* W2 = (const float*)d_in[5];   // [8,2048,1024]
  const float* b2 = (const float*)d_in[6];   // [8,1024]

  char* ws = (char*)d_ws;
  int*   cnt  = (int*)ws;                                  // 8 ints
  float* wts  = (float*)(ws + 256);                        // 16384 f32
  int*   eidx = (int*)(ws + 256 + 64 * 1024);              // 16384 int
  int*   list = (int*)(ws + 256 + 128 * 1024);             // 8*16384 int
  unsigned short* xc  = (unsigned short*)(ws + 1024 * 1024);     // 32 MB dense
  unsigned short* w1t = xc  + (size_t)16384 * 1024;              // 32 MB
  unsigned short* w2t = w1t + (size_t)8 * 2048 * 1024;           // 32 MB
  unsigned short* h   = w2t + (size_t)8 * 1024 * 2048;           // 64 MB

  constexpr int LDS_BYTES = 133120;
  hipFuncSetAttribute((const void*)gemm_moe8<1024, 2048, 1, 3>,
                      hipFuncAttributeMaxDynamicSharedMemorySize, LDS_BYTES);
  hipFuncSetAttribute((const void*)gemm_moe8<2048, 1024, 2, 2>,
                      hipFuncAttributeMaxDynamicSharedMemorySize, LDS_BYTES);

  hipMemsetAsync(cnt, 0, 32, stream);
  router_logits<<<dim3(4096), 256, 0, stream>>>(x, Wr, br, wts, eidx);
  bucketize<<<dim3(64), 256, 0, stream>>>(eidx, cnt, list);
  gather_compact<<<dim3(4096), 256, 0, stream>>>(x, cnt, list, xc);
  transpose_cvt<<<dim3(32, 16, 8), 256, 0, stream>>>(W1, w1t, 1024, 2048);
  transpose_cvt<<<dim3(16, 32, 8), 256, 0, stream>>>(W2, w2t, 2048, 1024);
  // worst-case m-blocks: sum_e ceil(cnt_e/256) <= 64+7 = 71
  gemm_moe8<1024, 2048, 1, 3><<<dim3(71 * 8), 512, LDS_BYTES, stream>>>(
      xc, w1t, b1, cnt, list, wts, (void*)h);
  gemm_moe8<2048, 1024, 2, 2><<<dim3(72 * 4), 512, LDS_BYTES, stream>>>(
      h, w2t, b2, cnt, list, wts, d_out);
}

// Round 6
// 352.223 us; speedup vs baseline: 1.2180x; 1.0504x over previous
//
#include <hip/hip_runtime.h>
#include <hip/hip_bf16.h>

// Switch-Transformer FFN, top-1 routing. B=4,S=4096,D=1024,F=2048,E=8.
// Pipeline: router_logits(+x->bf16) | bucketize | W1/W2 transpose->bf16 |
// grouped GEMM1 (gathered A, GELU, h bf16 dense by slot) |
// grouped GEMM2 (dense A, scale epi, scatter fp32).
// GEMM: 256x256, BK=32 subtiles, ring-4 LDS, ONE barrier + one vmcnt(8) +
// one lgkmcnt(0) per subtile, 32-MFMA setprio cluster, 0-conflict swizzle.

typedef __attribute__((ext_vector_type(8))) short short8;
typedef __attribute__((ext_vector_type(4))) float f32x4;

struct __align__(8) us4 { unsigned short x, y, z, w; };

__device__ __forceinline__ void gload16(const void* g, void* l) {
  __builtin_amdgcn_global_load_lds(
      (const __attribute__((address_space(1))) unsigned int*)g,
      (__attribute__((address_space(3))) unsigned int*)l, 16, 0, 0);
}

__device__ __forceinline__ unsigned short f2b(float f) {
  union { float f; unsigned u; } v; v.f = f;
  unsigned r = v.u + 0x7FFFu + ((v.u >> 16) & 1u);   // RNE
  return (unsigned short)(r >> 16);
}

// ---------------- router: logits, softmax top-1, expert id, x->bf16 ---------
__global__ __launch_bounds__(256) void router_logits(
    const float* __restrict__ x, const float* __restrict__ Wr,
    const float* __restrict__ br, float* __restrict__ wts,
    int* __restrict__ eidx, unsigned short* __restrict__ xb)
{
  const int lane = threadIdx.x & 63;
  const int wid  = threadIdx.x >> 6;
  const int t = blockIdx.x * 4 + wid;

  const float4* x4 = (const float4*)(x + (size_t)t * 1024);
  float acc[8];
#pragma unroll
  for (int e = 0; e < 8; ++e) acc[e] = 0.f;
#pragma unroll
  for (int i = 0; i < 4; ++i) {
    float4 v = x4[lane + 64 * i];
    const int d = (lane + 64 * i) * 4;
    const float* wr = Wr + (size_t)d * 8;
    float xs[4] = {v.x, v.y, v.z, v.w};
    us4 o;
    o.x = f2b(v.x); o.y = f2b(v.y); o.z = f2b(v.z); o.w = f2b(v.w);
    *(us4*)(xb + (size_t)t * 1024 + (size_t)(lane + 64 * i) * 4) = o;
#pragma unroll
    for (int j = 0; j < 4; ++j) {
      float4 w0 = *(const float4*)(wr + j * 8);
      float4 w1 = *(const float4*)(wr + j * 8 + 4);
      acc[0] += xs[j] * w0.x; acc[1] += xs[j] * w0.y;
      acc[2] += xs[j] * w0.z; acc[3] += xs[j] * w0.w;
      acc[4] += xs[j] * w1.x; acc[5] += xs[j] * w1.y;
      acc[6] += xs[j] * w1.z; acc[7] += xs[j] * w1.w;
    }
  }
#pragma unroll
  for (int e = 0; e < 8; ++e) {
    float v = acc[e];
#pragma unroll
    for (int m = 32; m; m >>= 1) v += __shfl_xor(v, m, 64);
    acc[e] = v;
  }
  if (lane == 0) {
    float lg[8];
#pragma unroll
    for (int e = 0; e < 8; ++e) lg[e] = acc[e] + br[e];
    float mx = lg[0]; int bi = 0;
#pragma unroll
    for (int e = 1; e < 8; ++e) if (lg[e] > mx) { mx = lg[e]; bi = e; }  // first-max == argmax
    float s = 0.f;
#pragma unroll
    for (int e = 0; e < 8; ++e) s += expf(lg[e] - mx);
    wts[t]  = 1.0f / s;
    eidx[t] = bi;
  }
}

// ---------------- bucketize ----------
__global__ __launch_bounds__(256) void bucketize(
    const int* __restrict__ eidx, int* __restrict__ cnt, int* __restrict__ list)
{
  __shared__ int lcnt[8], base[8];
  const int tid = threadIdx.x;
  if (tid < 8) lcnt[tid] = 0;
  __syncthreads();
  const int t = blockIdx.x * 256 + tid;
  const int e = eidx[t];
  const int lpos = atomicAdd(&lcnt[e], 1);
  __syncthreads();
  if (tid < 8) base[tid] = atomicAdd(&cnt[tid], lcnt[tid]);
  __syncthreads();
  list[e * 16384 + base[e] + lpos] = t;
}

// ---------------- W[k][n] fp32 -> Wt[n][k] bf16 ----------
__global__ __launch_bounds__(256) void transpose_cvt(
    const float* __restrict__ W, unsigned short* __restrict__ Wt, int K, int N)
{
  __shared__ float tl[64][65];
  const int e = blockIdx.z;
  const float* Wp = W + (size_t)e * K * N;
  unsigned short* Wtp = Wt + (size_t)e * K * N;
  const int k0 = blockIdx.y * 64, n0 = blockIdx.x * 64;
  const int r = threadIdx.x >> 4, c4 = (threadIdx.x & 15) * 4;
#pragma unroll
  for (int i = 0; i < 4; ++i) {
    float4 v = *(const float4*)(Wp + (size_t)(k0 + r + i * 16) * N + n0 + c4);
    tl[r + i * 16][c4 + 0] = v.x; tl[r + i * 16][c4 + 1] = v.y;
    tl[r + i * 16][c4 + 2] = v.z; tl[r + i * 16][c4 + 3] = v.w;
  }
  __syncthreads();
#pragma unroll
  for (int i = 0; i < 4; ++i) {
    const int n = r + i * 16;
    us4 o;
    o.x = f2b(tl[c4 + 0][n]); o.y = f2b(tl[c4 + 1][n]);
    o.z = f2b(tl[c4 + 2][n]); o.w = f2b(tl[c4 + 3][n]);
    *(us4*)(Wtp + (size_t)(n0 + n) * K + k0 + c4) = o;
  }
}

// ---------------- grouped GEMM: 256x256, ring-4, single-barrier schedule ----
// LDS: A ring 4x[256][32]bf16 @0; B ring @65536; tok@131072 wt@132096.
// Swizzle (measured 0-conflict): 16B-slot c of row r holds chunk c^((r>>1)&3).
// Per subtile T: { 12 ds_read (A8+B4, both halves) | STG_A+STG_B(T+3) |
//   lgkmcnt(0) | setprio(1) 32 MFMA setprio(0) | vmcnt(8) | s_barrier }.
// Safety: all reads of tile T-1 complete (lgkm0) before each wave's barrier
// arrival in iter T-1; slot (T+3)&3 == (T-1)&3 is only written in iter T,
// i.e. after that barrier. vmcnt(8) certifies tile T+1 (T+2,T+3 = 8 loads
// outstanding). Tail iterations re-stage tile NT-1 (dummy, drained at end).
// EPI1: A gathered via tok_s, h written dense by slot. EPI2: A dense,
// epilogue scatters to d_out[tok] * wt.
template <int K, int N, int EPI, int LOGNB>
__global__ __launch_bounds__(512, 2) void gemm_moe8(
    const unsigned short* __restrict__ A,    // EPI1: xb[16384][K] (token rows)
                                             // EPI2: h [16384][K] (slot rows)
    const unsigned short* __restrict__ Bt,   // [8][N][K] bf16
    const float* __restrict__ bias,          // [8][N]
    const int* __restrict__ cnt, const int* __restrict__ list,
    const float* __restrict__ wts, void* __restrict__ outp)
{
  constexpr int NT = K / 32;
  constexpr int NB = 1 << LOGNB;
  extern __shared__ char lds[];
  int*   tok_s = (int*)(lds + 131072);
  float* wt_s  = (float*)(lds + 132096);

  // ---- decode: XCD-chunked p -> (expert, mb, nb); nb fast (A-panel reuse)
  const int q = gridDim.x >> 3;
  const int p = ((int)blockIdx.x & 7) * q + ((int)blockIdx.x >> 3);
  int e = -1, pre = 0, cnte = 0, loc = p;
#pragma unroll
  for (int i = 0; i < 8; ++i) {
    const int c = cnt[i];
    const int bl = ((c + 255) >> 8) << LOGNB;
    if (e < 0) {
      if (loc < bl) { e = i; cnte = c; }
      else { loc -= bl; pre += c; }
    }
  }
  if (e < 0) return;
  const int row0 = (loc >> LOGNB) << 8;
  const int n0   = (loc & (NB - 1)) << 8;

  const int tid = threadIdx.x;
  const int lane = tid & 63, wid = tid >> 6;
  const int wr = wid >> 2, wc = wid & 3;     // wave output: rows wr*128, cols wc*64
  const int l15 = lane & 15;

  if (tid < 256) {
    const int s = row0 + tid;
    if (s < cnte) {
      const int t = list[e * 16384 + s];
      tok_s[tid] = t;
      wt_s[tid]  = (EPI == 2) ? wts[t] : 0.f;
    } else { tok_s[tid] = 0; wt_s[tid] = 0.f; }
  }
  __syncthreads();

  // ---- staging: thread covers rows {srow, 128+srow}, 16B slot (tid&3)
  const int srow = tid >> 2;                 // 0..127
  const int gch  = ((tid & 3) ^ ((srow >> 1) & 3)) * 8;   // pre-swizzled chunk
  const unsigned short* aG0;
  const unsigned short* aG1;
  if (EPI == 1) {                            // gathered token rows
    aG0 = A + (size_t)tok_s[srow] * K + gch;
    aG1 = A + (size_t)tok_s[128 + srow] * K + gch;
  } else {                                   // dense slot rows
    aG0 = A + (size_t)min(pre + row0 + srow, 16383) * K + gch;
    aG1 = A + (size_t)min(pre + row0 + 128 + srow, 16383) * K + gch;
  }
  const unsigned short* bG0 = Bt + ((size_t)e * N + n0 + srow) * K + gch;
  const unsigned short* bG1 = Bt + ((size_t)e * N + n0 + 128 + srow) * K + gch;

  // ---- fragment read bases (XOR folds to per-lane constant)
  const int xo = (((lane >> 4) ^ ((l15 >> 1) & 3)) << 4);
  const char* aB = lds + wr * 8192 + l15 * 64 + xo;           // + slot*16384 + m*1024
  const char* bB = lds + 65536 + wc * 4096 + l15 * 64 + xo;   // + slot*16384 + n*1024

  f32x4 acc[8][4];
#pragma unroll
  for (int m = 0; m < 8; ++m)
#pragma unroll
    for (int n = 0; n < 4; ++n) acc[m][n] = (f32x4){0.f, 0.f, 0.f, 0.f};

#define STG_A(S, T) do { \
    char* d_ = lds + (S) * 16384 + (wid << 10); \
    gload16(aG0 + (size_t)(T) * 32, d_); \
    gload16(aG1 + (size_t)(T) * 32, d_ + 8192); } while (0)
#define STG_B(S, T) do { \
    char* d_ = lds + 65536 + (S) * 16384 + (wid << 10); \
    gload16(bG0 + (size_t)(T) * 32, d_); \
    gload16(bG1 + (size_t)(T) * 32, d_ + 8192); } while (0)

  // ---- prologue: tiles 0,1,2 (12 loads); certify tile 0 (8 outstanding)
  STG_A(0, 0); STG_B(0, 0);
  STG_A(1, 1); STG_B(1, 1);
  STG_A(2, 2); STG_B(2, 2);
  asm volatile("s_waitcnt vmcnt(8)" ::: "memory");
  __builtin_amdgcn_s_barrier();

  short8 aF[8], bF[4];
#pragma unroll 1
  for (int T = 0; T < NT; ++T) {
    const int slot = T & 3;
    const int ss   = (T + 3) & 3;
    const int Ts   = (T + 3 < NT) ? T + 3 : NT - 1;   // dummy restage at tail
    const char* aT = aB + slot * 16384;
    const char* bT = bB + slot * 16384;
    // all 12 fragment reads for this subtile (both MFMA half-clusters)
#pragma unroll
    for (int m = 0; m < 8; ++m) aF[m] = *(const short8*)(aT + m * 1024);
#pragma unroll
    for (int n = 0; n < 4; ++n) bF[n] = *(const short8*)(bT + n * 1024);
    STG_A(ss, Ts);
    STG_B(ss, Ts);
    asm volatile("s_waitcnt lgkmcnt(0)" ::: "memory");
    __builtin_amdgcn_sched_barrier(0);
    __builtin_amdgcn_s_setprio(1);
#pragma unroll
    for (int m = 0; m < 8; ++m)
#pragma unroll
      for (int n = 0; n < 4; ++n)
        acc[m][n] = __builtin_amdgcn_mfma_f32_16x16x32_bf16(
            aF[m], bF[n], acc[m][n], 0, 0, 0);
    __builtin_amdgcn_s_setprio(0);
    __builtin_amdgcn_sched_barrier(0);
    asm volatile("s_waitcnt vmcnt(8)" ::: "memory");   // certify tile T+1
    __builtin_amdgcn_s_barrier();
  }
#undef STG_A
#undef STG_B
  asm volatile("s_waitcnt vmcnt(0)" ::: "memory");     // drain dummy stages

  // ---- epilogue; C frag: col = lane&15, row = (lane>>4)*4 + r
  const int cRow0 = wr * 128 + ((lane >> 4) << 2);
  const int cColB = n0 + wc * 64 + l15;
  float bv[4];
#pragma unroll
  for (int nf = 0; nf < 4; ++nf) bv[nf] = bias[e * N + cColB + nf * 16];

  if (EPI == 1) {
    unsigned short* H = (unsigned short*)outp;
#pragma unroll
    for (int m = 0; m < 8; ++m)
#pragma unroll
      for (int r = 0; r < 4; ++r) {
        const int sl = cRow0 + m * 16 + r;
        if (row0 + sl < cnte) {
          const size_t rp = (size_t)(pre + row0 + sl) * N + cColB;
#pragma unroll
          for (int nf = 0; nf < 4; ++nf) {
            float v = acc[m][nf][r] + bv[nf];
            // tanh-form GELU via exp (dev <= ~1e-3 vs erf; threshold 3.4e-2)
            float u = 1.5957691216f * v * (1.0f + 0.044715f * v * v);
            float ex = __expf(u);
            float th = 1.0f - 2.0f / (ex + 1.0f);
            v = 0.5f * v * (1.0f + th);
            H[rp + nf * 16] = f2b(v);
          }
        }
      }
  } else {
    float* O = (float*)outp;
#pragma unroll
    for (int m = 0; m < 8; ++m)
#pragma unroll
      for (int r = 0; r < 4; ++r) {
        const int sl = cRow0 + m * 16 + r;
        if (row0 + sl < cnte) {
          const size_t rp = (size_t)tok_s[sl] * N + cColB;
          const float w = wt_s[sl];
#pragma unroll
          for (int nf = 0; nf < 4; ++nf)
            O[rp + nf * 16] = (acc[m][nf][r] + bv[nf]) * w;
        }
      }
  }
}

// ---------------------------------------------------------------------------
extern "C" void kernel_launch(void* const* d_in, const int* in_sizes, int n_in,
                              void* d_out, int out_size, void* d_ws, size_t ws_size,
                              hipStream_t stream) {
  const float* x  = (const float*)d_in[0];   // [4,4096,1024]
  const float* Wr = (const float*)d_in[1];   // [1024,8]
  const float* br = (const float*)d_in[2];   // [8]
  const float* W1 = (const float*)d_in[3];   // [8,1024,2048]
  const float* b1 = (const float*)d_in[4];   // [8,2048]
  const float* W2 = (const float*)d_in[5];   // [8,2048,1024]
  const float* b2 = (const float*)d_in[6];   // [8,1024]

  char* ws = (char*)d_ws;
  int*   cnt  = (int*)ws;                                  // 8 ints
  float* wts  = (float*)(ws + 256);                        // 16384 f32
  int*   eidx = (int*)(ws + 256 + 64 * 1024);              // 16384 int
  int*   list = (int*)(ws + 256 + 128 * 1024);             // 8*16384 int
  unsigned short* xb  = (unsigned short*)(ws + 1024 * 1024);     // 32 MB token rows
  unsigned short* w1t = xb  + (size_t)16384 * 1024;              // 32 MB
  unsigned short* w2t = w1t + (size_t)8 * 2048 * 1024;           // 32 MB
  unsigned short* h   = w2t + (size_t)8 * 1024 * 2048;           // 64 MB slot rows

  constexpr int LDS_BYTES = 133120;
  hipFuncSetAttribute((const void*)gemm_moe8<1024, 2048, 1, 3>,
                      hipFuncAttributeMaxDynamicSharedMemorySize, LDS_BYTES);
  hipFuncSetAttribute((const void*)gemm_moe8<2048, 1024, 2, 2>,
                      hipFuncAttributeMaxDynamicSharedMemorySize, LDS_BYTES);

  hipMemsetAsync(cnt, 0, 32, stream);
  router_logits<<<dim3(4096), 256, 0, stream>>>(x, Wr, br, wts, eidx, xb);
  bucketize<<<dim3(64), 256, 0, stream>>>(eidx, cnt, list);
  transpose_cvt<<<dim3(32, 16, 8), 256, 0, stream>>>(W1, w1t, 1024, 2048);
  transpose_cvt<<<dim3(16, 32, 8), 256, 0, stream>>>(W2, w2t, 2048, 1024);
  // worst-case m-blocks: sum_e ceil(cnt_e/256) <= 64+7 = 71
  gemm_moe8<1024, 2048, 1, 3><<<dim3(71 * 8), 512, LDS_BYTES, stream>>>(
      xb, w1t, b1, cnt, list, wts, (void*)h);
  gemm_moe8<2048, 1024, 2, 2><<<dim3(71 * 4), 512, LDS_BYTES, stream>>>(
      h, w2t, b2, cnt, list, wts, d_out);
}